// Round 5
// baseline (2041.083 us; speedup 1.0000x reference)
//
#include <hip/hip_runtime.h>
#include <hip/hip_bf16.h>

// MHA forward: B=2,S=2048,D=1024,H=16,DK=64. fp32 I/O (bf16-validation mode),
// bf16 MFMA compute with fp32 accumulate.
// d_out (fp32, concat): output (B,S,D) then attn (B,H,S,S).
// Certified 5-kernel pipeline + guarded bf16-P fast path for pv.

#define B_  2
#define S_  2048
#define D_  1024
#define H_  16
#define DK_ 64

typedef short bf16x8 __attribute__((ext_vector_type(8)));   // 8 bf16 in 4 VGPRs
typedef float f32x4  __attribute__((ext_vector_type(4)));

__device__ __forceinline__ f32x4 mfma16(bf16x8 a, bf16x8 b, f32x4 c) {
    return __builtin_amdgcn_mfma_f32_16x16x32_bf16(a, b, c, 0, 0, 0);
}

__device__ __forceinline__ short f2bf(float f) {
    unsigned u = __builtin_bit_cast(unsigned, f);
    u += 0x7FFFu + ((u >> 16) & 1u);          // round-to-nearest-even
    return (short)(u >> 16);
}

// load 8 contiguous fp32 (32B, aligned) -> bf16x8 fragment
__device__ __forceinline__ bf16x8 load8f_bf(const float* __restrict__ p) {
    f32x4 x0 = *reinterpret_cast<const f32x4*>(p);
    f32x4 x1 = *reinterpret_cast<const f32x4*>(p + 4);
    bf16x8 r;
#pragma unroll
    for (int i = 0; i < 4; ++i) { r[i] = f2bf(x0[i]); r[i + 4] = f2bf(x1[i]); }
    return r;
}

__device__ __forceinline__ bf16x8 load8b(const __hip_bfloat16* __restrict__ p) {
    return *reinterpret_cast<const bf16x8*>(p);
}

__device__ __forceinline__ bf16x8 load8s(const short* __restrict__ p) {
    return *reinterpret_cast<const bf16x8*>(p);
}

// ---------------------------------------------------------------------------
// Input projections: C[m][n] = sum_k X[m*1024+k] * W[n*1024+k] + bias[n]
// X, W fp32; output bf16 workspace.
// mode 0: head-split (B,H,S,DK)  (Q, K)    mode 1: transposed (B,H,DK,S)  (V)
// One 16x16 tile per wave; block = 4 waves = 64 rows x 16 cols.
// ---------------------------------------------------------------------------
__global__ __launch_bounds__(256) void proj_in_kernel(
    const float* __restrict__ X, const float* __restrict__ W,
    const float* __restrict__ bias, __hip_bfloat16* __restrict__ out, int mode)
{
    const int wave = threadIdx.x >> 6;
    const int lane = threadIdx.x & 63;
    const int row  = lane & 15;
    const int quad = lane >> 4;
    const int n0 = blockIdx.x * 16;
    const int m0 = (blockIdx.y * 4 + wave) * 16;

    const float* xa = X + (size_t)(m0 + row) * D_ + quad * 8;
    const float* wb = W + (size_t)(n0 + row) * D_ + quad * 8;

    f32x4 acc = {0.f, 0.f, 0.f, 0.f};
    for (int kk = 0; kk < D_; kk += 32)
        acc = mfma16(load8f_bf(xa + kk), load8f_bf(wb + kk), acc);

    const int n = n0 + row;                       // C col = lane&15
    const float bv = bias[n];
    const int h = n >> 6, d = n & 63;
#pragma unroll
    for (int r = 0; r < 4; ++r) {
        const int m = m0 + quad * 4 + r;          // C row = quad*4 + reg
        const int b = m >> 11, s = m & 2047;
        const float v = acc[r] + bv;
        size_t off = (mode == 0)
            ? (((size_t)b * H_ + h) * S_ + s) * DK_ + d
            : (((size_t)b * H_ + h) * DK_ + d) * S_ + s;
        out[off] = __float2bfloat16(v);
    }
}

// ---------------------------------------------------------------------------
// Output projection: ctx (bf16, B,S,D) @ Wo^T (fp32) + bo -> fp32 out (B,S,D)
// ---------------------------------------------------------------------------
__global__ __launch_bounds__(256) void proj_out_kernel(
    const __hip_bfloat16* __restrict__ X, const float* __restrict__ W,
    const float* __restrict__ bias, float* __restrict__ out)
{
    const int wave = threadIdx.x >> 6;
    const int lane = threadIdx.x & 63;
    const int row  = lane & 15;
    const int quad = lane >> 4;
    const int n0 = blockIdx.x * 16;
    const int m0 = (blockIdx.y * 4 + wave) * 16;

    const __hip_bfloat16* xa = X + (size_t)(m0 + row) * D_ + quad * 8;
    const float* wb = W + (size_t)(n0 + row) * D_ + quad * 8;

    f32x4 acc = {0.f, 0.f, 0.f, 0.f};
    for (int kk = 0; kk < D_; kk += 32)
        acc = mfma16(load8b(xa + kk), load8f_bf(wb + kk), acc);

    const int n = n0 + row;
    const float bv = bias[n];
#pragma unroll
    for (int r = 0; r < 4; ++r) {
        const int m = m0 + quad * 4 + r;
        out[(size_t)m * D_ + n] = acc[r] + bv;
    }
}

// ---------------------------------------------------------------------------
// Pass 1: per-row sum of exp(scores). Grid (S/16, B*H), block 256.
// Wave w handles 16 query rows x keys [w*512, w*512+512).
// No max-subtraction: |score| <~ 7 << 88; softmax is shift-invariant.
// ---------------------------------------------------------------------------
__global__ __launch_bounds__(256) void rowsum_kernel(
    const __hip_bfloat16* __restrict__ Q, const __hip_bfloat16* __restrict__ Kh,
    float* __restrict__ invl)
{
    __shared__ float red[4][16];
    const int wave = threadIdx.x >> 6;
    const int lane = threadIdx.x & 63;
    const int row  = lane & 15;
    const int quad = lane >> 4;
    const int bh = blockIdx.y;
    const int s0 = blockIdx.x * 16;

    const __hip_bfloat16* qbase = Q + ((size_t)bh * S_ + s0 + row) * DK_ + quad * 8;
    const bf16x8 a0 = load8b(qbase);
    const bf16x8 a1 = load8b(qbase + 32);
    const __hip_bfloat16* kbase = Kh + (size_t)bh * S_ * DK_;

    float sums[4] = {0.f, 0.f, 0.f, 0.f};
    for (int t = 0; t < 32; ++t) {
        const int c0 = wave * 512 + t * 16;
        const __hip_bfloat16* kb = kbase + (size_t)(c0 + row) * DK_ + quad * 8;
        f32x4 acc = {0.f, 0.f, 0.f, 0.f};
        acc = mfma16(a0, load8b(kb), acc);
        acc = mfma16(a1, load8b(kb + 32), acc);
#pragma unroll
        for (int r = 0; r < 4; ++r)
            sums[r] += __expf(acc[r] * 0.125f);
    }
#pragma unroll
    for (int m = 1; m < 16; m <<= 1) {        // reduce over 16 cols (lane&15)
#pragma unroll
        for (int r = 0; r < 4; ++r)
            sums[r] += __shfl_xor(sums[r], m, 64);
    }
    if (row == 0) {
#pragma unroll
        for (int r = 0; r < 4; ++r) red[wave][quad * 4 + r] = sums[r];
    }
    __syncthreads();
    if (threadIdx.x < 16) {
        float l = red[0][threadIdx.x] + red[1][threadIdx.x]
                + red[2][threadIdx.x] + red[3][threadIdx.x];
        invl[(size_t)bh * S_ + s0 + threadIdx.x] = 1.0f / l;
    }
}

// ---------------------------------------------------------------------------
// Pass 2: recompute scores, write normalized fp32 attn to d_out. (certified)
// ---------------------------------------------------------------------------
__global__ __launch_bounds__(256) void attn_kernel(
    const __hip_bfloat16* __restrict__ Q, const __hip_bfloat16* __restrict__ Kh,
    const float* __restrict__ invl, float* __restrict__ attn)
{
    const int wave = threadIdx.x >> 6;
    const int lane = threadIdx.x & 63;
    const int row  = lane & 15;
    const int quad = lane >> 4;
    const int bh = blockIdx.y;
    const int s0 = blockIdx.x * 16;

    const __hip_bfloat16* qbase = Q + ((size_t)bh * S_ + s0 + row) * DK_ + quad * 8;
    const bf16x8 a0 = load8b(qbase);
    const bf16x8 a1 = load8b(qbase + 32);
    float il[4];
#pragma unroll
    for (int r = 0; r < 4; ++r)
        il[r] = invl[(size_t)bh * S_ + s0 + quad * 4 + r];

    const __hip_bfloat16* kbase = Kh + (size_t)bh * S_ * DK_;
    float* abase = attn + ((size_t)bh * S_ + s0) * S_;

    for (int t = 0; t < 32; ++t) {
        const int c0 = wave * 512 + t * 16;
        const __hip_bfloat16* kb = kbase + (size_t)(c0 + row) * DK_ + quad * 8;
        f32x4 acc = {0.f, 0.f, 0.f, 0.f};
        acc = mfma16(a0, load8b(kb), acc);
        acc = mfma16(a1, load8b(kb + 32), acc);
        const int col = c0 + row;
#pragma unroll
        for (int r = 0; r < 4; ++r)
            abase[(size_t)(quad * 4 + r) * S_ + col] =
                __expf(acc[r] * 0.125f) * il[r];
    }
}

// ---------------------------------------------------------------------------
// Pass 2 variant: same as attn_kernel, plus bf16 copy of P to workspace
// (same scatter pattern; f2bf matches the rounding pv applied on load).
// ---------------------------------------------------------------------------
__global__ __launch_bounds__(256) void attn_kernel_pb(
    const __hip_bfloat16* __restrict__ Q, const __hip_bfloat16* __restrict__ Kh,
    const float* __restrict__ invl, float* __restrict__ attn,
    short* __restrict__ Pb)
{
    const int wave = threadIdx.x >> 6;
    const int lane = threadIdx.x & 63;
    const int row  = lane & 15;
    const int quad = lane >> 4;
    const int bh = blockIdx.y;
    const int s0 = blockIdx.x * 16;

    const __hip_bfloat16* qbase = Q + ((size_t)bh * S_ + s0 + row) * DK_ + quad * 8;
    const bf16x8 a0 = load8b(qbase);
    const bf16x8 a1 = load8b(qbase + 32);
    float il[4];
#pragma unroll
    for (int r = 0; r < 4; ++r)
        il[r] = invl[(size_t)bh * S_ + s0 + quad * 4 + r];

    const __hip_bfloat16* kbase = Kh + (size_t)bh * S_ * DK_;
    float* abase = attn + ((size_t)bh * S_ + s0) * S_;
    short* pbase = Pb + ((size_t)bh * S_ + s0) * S_;

    for (int t = 0; t < 32; ++t) {
        const int c0 = wave * 512 + t * 16;
        const __hip_bfloat16* kb = kbase + (size_t)(c0 + row) * DK_ + quad * 8;
        f32x4 acc = {0.f, 0.f, 0.f, 0.f};
        acc = mfma16(a0, load8b(kb), acc);
        acc = mfma16(a1, load8b(kb + 32), acc);
        const int col = c0 + row;
#pragma unroll
        for (int r = 0; r < 4; ++r) {
            const float p = __expf(acc[r] * 0.125f) * il[r];
            abase[(size_t)(quad * 4 + r) * S_ + col] = p;
            pbase[(size_t)(quad * 4 + r) * S_ + col] = f2bf(p);
        }
    }
}

// ---------------------------------------------------------------------------
// PV: context = attn @ V. Grid (S/16, B*H); wave = n-tile. (certified fp32 path)
// Vt layout (B,H,DK,S) makes B-fragments contiguous. ctx written (B,S,H,DK).
// ---------------------------------------------------------------------------
__global__ __launch_bounds__(256) void pv_kernel(
    const float* __restrict__ attn, const __hip_bfloat16* __restrict__ Vt,
    __hip_bfloat16* __restrict__ ctx)
{
    const int wave = threadIdx.x >> 6;
    const int lane = threadIdx.x & 63;
    const int row  = lane & 15;
    const int quad = lane >> 4;
    const int bh = blockIdx.y;
    const int b = bh >> 4, h = bh & 15;
    const int m0 = blockIdx.x * 16;
    const int n0 = wave * 16;

    const float* abase = attn + ((size_t)bh * S_ + m0 + row) * S_ + quad * 8;
    const __hip_bfloat16* vbase = Vt + ((size_t)bh * DK_ + n0 + row) * S_ + quad * 8;

    f32x4 acc = {0.f, 0.f, 0.f, 0.f};
    for (int kk = 0; kk < S_; kk += 32)
        acc = mfma16(load8f_bf(abase + kk), load8b(vbase + kk), acc);

    const int d = n0 + row;
#pragma unroll
    for (int r = 0; r < 4; ++r) {
        const int s = m0 + quad * 4 + r;
        ctx[(((size_t)b * S_ + s) * H_ + h) * DK_ + d] = __float2bfloat16(acc[r]);
    }
}

// ---------------------------------------------------------------------------
// PV bf16-P variant: identical indexing, reads Pb (bf16) -> half the fetch,
// no per-element conversion.
// ---------------------------------------------------------------------------
__global__ __launch_bounds__(256) void pv_kernel_pb(
    const short* __restrict__ Pb, const __hip_bfloat16* __restrict__ Vt,
    __hip_bfloat16* __restrict__ ctx)
{
    const int wave = threadIdx.x >> 6;
    const int lane = threadIdx.x & 63;
    const int row  = lane & 15;
    const int quad = lane >> 4;
    const int bh = blockIdx.y;
    const int b = bh >> 4, h = bh & 15;
    const int m0 = blockIdx.x * 16;
    const int n0 = wave * 16;

    const short* abase = Pb + ((size_t)bh * S_ + m0 + row) * S_ + quad * 8;
    const __hip_bfloat16* vbase = Vt + ((size_t)bh * DK_ + n0 + row) * S_ + quad * 8;

    f32x4 acc = {0.f, 0.f, 0.f, 0.f};
    for (int kk = 0; kk < S_; kk += 32)
        acc = mfma16(load8s(abase + kk), load8b(vbase + kk), acc);

    const int d = n0 + row;
#pragma unroll
    for (int r = 0; r < 4; ++r) {
        const int s = m0 + quad * 4 + r;
        ctx[(((size_t)b * S_ + s) * H_ + h) * DK_ + d] = __float2bfloat16(acc[r]);
    }
}

// ---------------------------------------------------------------------------
extern "C" void kernel_launch(void* const* d_in, const int* in_sizes, int n_in,
                              void* d_out, int out_size, void* d_ws, size_t ws_size,
                              hipStream_t stream)
{
    const float* query = (const float*)d_in[0];
    const float* key   = (const float*)d_in[1];
    const float* value = (const float*)d_in[2];
    const float* Wq = (const float*)d_in[3];
    const float* bq = (const float*)d_in[4];
    const float* Wk = (const float*)d_in[5];
    const float* bk = (const float*)d_in[6];
    const float* Wv = (const float*)d_in[7];
    const float* bv = (const float*)d_in[8];
    const float* Wo = (const float*)d_in[9];
    const float* bo = (const float*)d_in[10];

    float* out      = (float*)d_out;
    float* attn_out = out + (size_t)B_ * S_ * D_;

    const size_t NBSD = (size_t)B_ * S_ * D_;     // 4,194,304 elems
    __hip_bfloat16* q_ws   = (__hip_bfloat16*)d_ws;
    __hip_bfloat16* k_ws   = q_ws + NBSD;
    __hip_bfloat16* vt_ws  = k_ws + NBSD;
    __hip_bfloat16* ctx_ws = vt_ws + NBSD;
    float*          invl   = (float*)(ctx_ws + NBSD);
    short*          pb_ws  = (short*)(invl + (size_t)B_ * H_ * S_);

    // bytes needed for the bf16-P fast path
    const size_t need_pb = (size_t)NBSD * 2 * 4                 // q,k,vt,ctx
                         + (size_t)B_ * H_ * S_ * 4             // invl
                         + (size_t)B_ * H_ * S_ * S_ * 2;       // Pb
    const bool use_pb = (ws_size >= need_pb);

    dim3 blk(256);
    dim3 gproj(D_ / 16, (B_ * S_) / 64);
    dim3 gatt(S_ / 16, B_ * H_);

    proj_in_kernel<<<gproj, blk, 0, stream>>>(query, Wq, bq, q_ws, 0);
    proj_in_kernel<<<gproj, blk, 0, stream>>>(key,   Wk, bk, k_ws, 0);
    proj_in_kernel<<<gproj, blk, 0, stream>>>(value, Wv, bv, vt_ws, 1);
    rowsum_kernel<<<gatt, blk, 0, stream>>>(q_ws, k_ws, invl);
    if (use_pb) {
        attn_kernel_pb<<<gatt, blk, 0, stream>>>(q_ws, k_ws, invl, attn_out, pb_ws);
        pv_kernel_pb<<<gatt, blk, 0, stream>>>(pb_ws, vt_ws, ctx_ws);
    } else {
        attn_kernel<<<gatt, blk, 0, stream>>>(q_ws, k_ws, invl, attn_out);
        pv_kernel<<<gatt, blk, 0, stream>>>(attn_out, vt_ws, ctx_ws);
    }
    proj_out_kernel<<<gproj, blk, 0, stream>>>(ctx_ws, Wo, bo, out);
}

// Round 6
// 1666.306 us; speedup vs baseline: 1.2249x; 1.2249x over previous
//
#include <hip/hip_runtime.h>
#include <hip/hip_bf16.h>

// MHA forward: B=2,S=2048,D=1024,H=16,DK=64. fp32 I/O (bf16-validation mode),
// bf16 MFMA compute with fp32 accumulate.
// d_out (fp32, concat): output (B,S,D) then attn (B,H,S,S).
// Pipeline: pre-convert X/W to bf16 once -> bf16 proj GEMMs -> rowsum ->
// attn (+bf16 P copy) -> PV(bf16 P) -> proj_out. Guarded by ws_size with
// fallback to the certified fp32 pipeline.

#define B_  2
#define S_  2048
#define D_  1024
#define H_  16
#define DK_ 64

typedef short bf16x8 __attribute__((ext_vector_type(8)));   // 8 bf16 in 4 VGPRs
typedef float f32x4  __attribute__((ext_vector_type(4)));

__device__ __forceinline__ f32x4 mfma16(bf16x8 a, bf16x8 b, f32x4 c) {
    return __builtin_amdgcn_mfma_f32_16x16x32_bf16(a, b, c, 0, 0, 0);
}

__device__ __forceinline__ short f2bf(float f) {
    unsigned u = __builtin_bit_cast(unsigned, f);
    u += 0x7FFFu + ((u >> 16) & 1u);          // round-to-nearest-even
    return (short)(u >> 16);
}

// load 8 contiguous fp32 (32B, aligned) -> bf16x8 fragment
__device__ __forceinline__ bf16x8 load8f_bf(const float* __restrict__ p) {
    f32x4 x0 = *reinterpret_cast<const f32x4*>(p);
    f32x4 x1 = *reinterpret_cast<const f32x4*>(p + 4);
    bf16x8 r;
#pragma unroll
    for (int i = 0; i < 4; ++i) { r[i] = f2bf(x0[i]); r[i + 4] = f2bf(x1[i]); }
    return r;
}

__device__ __forceinline__ bf16x8 load8b(const __hip_bfloat16* __restrict__ p) {
    return *reinterpret_cast<const bf16x8*>(p);
}

__device__ __forceinline__ bf16x8 load8s(const short* __restrict__ p) {
    return *reinterpret_cast<const bf16x8*>(p);
}

// ---------------------------------------------------------------------------
// Elementwise fp32 -> bf16 (same f2bf rounding as the GEMM loads used).
// n must be a multiple of 8. Grid-stride, vectorized 32B/16B.
// ---------------------------------------------------------------------------
__global__ __launch_bounds__(256) void cvt_bf16_kernel(
    const float* __restrict__ in, short* __restrict__ out, int n)
{
    const int stride = gridDim.x * 256 * 8;
    for (int i = (blockIdx.x * 256 + threadIdx.x) * 8; i < n; i += stride) {
        f32x4 x0 = *reinterpret_cast<const f32x4*>(in + i);
        f32x4 x1 = *reinterpret_cast<const f32x4*>(in + i + 4);
        bf16x8 r;
#pragma unroll
        for (int j = 0; j < 4; ++j) { r[j] = f2bf(x0[j]); r[j + 4] = f2bf(x1[j]); }
        *reinterpret_cast<bf16x8*>(out + i) = r;
    }
}

// ---------------------------------------------------------------------------
// Input projections, bf16 operands (pre-converted):
// C[m][n] = sum_k X[m*1024+k] * W[n*1024+k] + bias[n]
// mode 0: head-split (B,H,S,DK)  (Q, K)    mode 1: transposed (B,H,DK,S)  (V)
// One 16x16 tile per wave; block = 4 waves = 64 rows x 16 cols.
// ---------------------------------------------------------------------------
__global__ __launch_bounds__(256) void proj_in_bf_kernel(
    const short* __restrict__ X, const short* __restrict__ W,
    const float* __restrict__ bias, __hip_bfloat16* __restrict__ out, int mode)
{
    const int wave = threadIdx.x >> 6;
    const int lane = threadIdx.x & 63;
    const int row  = lane & 15;
    const int quad = lane >> 4;
    const int n0 = blockIdx.x * 16;
    const int m0 = (blockIdx.y * 4 + wave) * 16;

    const short* xa = X + (size_t)(m0 + row) * D_ + quad * 8;
    const short* wb = W + (size_t)(n0 + row) * D_ + quad * 8;

    f32x4 acc = {0.f, 0.f, 0.f, 0.f};
    for (int kk = 0; kk < D_; kk += 32)
        acc = mfma16(load8s(xa + kk), load8s(wb + kk), acc);

    const int n = n0 + row;                       // C col = lane&15
    const float bv = bias[n];
    const int h = n >> 6, d = n & 63;
#pragma unroll
    for (int r = 0; r < 4; ++r) {
        const int m = m0 + quad * 4 + r;          // C row = quad*4 + reg
        const int b = m >> 11, s = m & 2047;
        const float v = acc[r] + bv;
        size_t off = (mode == 0)
            ? (((size_t)b * H_ + h) * S_ + s) * DK_ + d
            : (((size_t)b * H_ + h) * DK_ + d) * S_ + s;
        out[off] = __float2bfloat16(v);
    }
}

// fp32-operand variant (fallback path; certified)
__global__ __launch_bounds__(256) void proj_in_kernel(
    const float* __restrict__ X, const float* __restrict__ W,
    const float* __restrict__ bias, __hip_bfloat16* __restrict__ out, int mode)
{
    const int wave = threadIdx.x >> 6;
    const int lane = threadIdx.x & 63;
    const int row  = lane & 15;
    const int quad = lane >> 4;
    const int n0 = blockIdx.x * 16;
    const int m0 = (blockIdx.y * 4 + wave) * 16;

    const float* xa = X + (size_t)(m0 + row) * D_ + quad * 8;
    const float* wb = W + (size_t)(n0 + row) * D_ + quad * 8;

    f32x4 acc = {0.f, 0.f, 0.f, 0.f};
    for (int kk = 0; kk < D_; kk += 32)
        acc = mfma16(load8f_bf(xa + kk), load8f_bf(wb + kk), acc);

    const int n = n0 + row;
    const float bv = bias[n];
    const int h = n >> 6, d = n & 63;
#pragma unroll
    for (int r = 0; r < 4; ++r) {
        const int m = m0 + quad * 4 + r;
        const int b = m >> 11, s = m & 2047;
        const float v = acc[r] + bv;
        size_t off = (mode == 0)
            ? (((size_t)b * H_ + h) * S_ + s) * DK_ + d
            : (((size_t)b * H_ + h) * DK_ + d) * S_ + s;
        out[off] = __float2bfloat16(v);
    }
}

// ---------------------------------------------------------------------------
// Output projection: ctx (bf16) @ Wo^T + bo -> fp32 out (B,S,D)
// bf16-Wo variant (fast path) and fp32-Wo variant (fallback).
// ---------------------------------------------------------------------------
__global__ __launch_bounds__(256) void proj_out_bf_kernel(
    const __hip_bfloat16* __restrict__ X, const short* __restrict__ W,
    const float* __restrict__ bias, float* __restrict__ out)
{
    const int wave = threadIdx.x >> 6;
    const int lane = threadIdx.x & 63;
    const int row  = lane & 15;
    const int quad = lane >> 4;
    const int n0 = blockIdx.x * 16;
    const int m0 = (blockIdx.y * 4 + wave) * 16;

    const __hip_bfloat16* xa = X + (size_t)(m0 + row) * D_ + quad * 8;
    const short* wb = W + (size_t)(n0 + row) * D_ + quad * 8;

    f32x4 acc = {0.f, 0.f, 0.f, 0.f};
    for (int kk = 0; kk < D_; kk += 32)
        acc = mfma16(load8b(xa + kk), load8s(wb + kk), acc);

    const int n = n0 + row;
    const float bv = bias[n];
#pragma unroll
    for (int r = 0; r < 4; ++r) {
        const int m = m0 + quad * 4 + r;
        out[(size_t)m * D_ + n] = acc[r] + bv;
    }
}

__global__ __launch_bounds__(256) void proj_out_kernel(
    const __hip_bfloat16* __restrict__ X, const float* __restrict__ W,
    const float* __restrict__ bias, float* __restrict__ out)
{
    const int wave = threadIdx.x >> 6;
    const int lane = threadIdx.x & 63;
    const int row  = lane & 15;
    const int quad = lane >> 4;
    const int n0 = blockIdx.x * 16;
    const int m0 = (blockIdx.y * 4 + wave) * 16;

    const __hip_bfloat16* xa = X + (size_t)(m0 + row) * D_ + quad * 8;
    const float* wb = W + (size_t)(n0 + row) * D_ + quad * 8;

    f32x4 acc = {0.f, 0.f, 0.f, 0.f};
    for (int kk = 0; kk < D_; kk += 32)
        acc = mfma16(load8b(xa + kk), load8f_bf(wb + kk), acc);

    const int n = n0 + row;
    const float bv = bias[n];
#pragma unroll
    for (int r = 0; r < 4; ++r) {
        const int m = m0 + quad * 4 + r;
        out[(size_t)m * D_ + n] = acc[r] + bv;
    }
}

// ---------------------------------------------------------------------------
// Pass 1: per-row sum of exp(scores). Grid (S/16, B*H), block 256.
// Wave w handles 16 query rows x keys [w*512, w*512+512).
// No max-subtraction: |score| <~ 7 << 88; softmax is shift-invariant.
// ---------------------------------------------------------------------------
__global__ __launch_bounds__(256) void rowsum_kernel(
    const __hip_bfloat16* __restrict__ Q, const __hip_bfloat16* __restrict__ Kh,
    float* __restrict__ invl)
{
    __shared__ float red[4][16];
    const int wave = threadIdx.x >> 6;
    const int lane = threadIdx.x & 63;
    const int row  = lane & 15;
    const int quad = lane >> 4;
    const int bh = blockIdx.y;
    const int s0 = blockIdx.x * 16;

    const __hip_bfloat16* qbase = Q + ((size_t)bh * S_ + s0 + row) * DK_ + quad * 8;
    const bf16x8 a0 = load8b(qbase);
    const bf16x8 a1 = load8b(qbase + 32);
    const __hip_bfloat16* kbase = Kh + (size_t)bh * S_ * DK_;

    float sums[4] = {0.f, 0.f, 0.f, 0.f};
    for (int t = 0; t < 32; ++t) {
        const int c0 = wave * 512 + t * 16;
        const __hip_bfloat16* kb = kbase + (size_t)(c0 + row) * DK_ + quad * 8;
        f32x4 acc = {0.f, 0.f, 0.f, 0.f};
        acc = mfma16(a0, load8b(kb), acc);
        acc = mfma16(a1, load8b(kb + 32), acc);
#pragma unroll
        for (int r = 0; r < 4; ++r)
            sums[r] += __expf(acc[r] * 0.125f);
    }
#pragma unroll
    for (int m = 1; m < 16; m <<= 1) {        // reduce over 16 cols (lane&15)
#pragma unroll
        for (int r = 0; r < 4; ++r)
            sums[r] += __shfl_xor(sums[r], m, 64);
    }
    if (row == 0) {
#pragma unroll
        for (int r = 0; r < 4; ++r) red[wave][quad * 4 + r] = sums[r];
    }
    __syncthreads();
    if (threadIdx.x < 16) {
        float l = red[0][threadIdx.x] + red[1][threadIdx.x]
                + red[2][threadIdx.x] + red[3][threadIdx.x];
        invl[(size_t)bh * S_ + s0 + threadIdx.x] = 1.0f / l;
    }
}

// ---------------------------------------------------------------------------
// Pass 2: recompute scores, write normalized fp32 attn to d_out. (certified)
// ---------------------------------------------------------------------------
__global__ __launch_bounds__(256) void attn_kernel(
    const __hip_bfloat16* __restrict__ Q, const __hip_bfloat16* __restrict__ Kh,
    const float* __restrict__ invl, float* __restrict__ attn)
{
    const int wave = threadIdx.x >> 6;
    const int lane = threadIdx.x & 63;
    const int row  = lane & 15;
    const int quad = lane >> 4;
    const int bh = blockIdx.y;
    const int s0 = blockIdx.x * 16;

    const __hip_bfloat16* qbase = Q + ((size_t)bh * S_ + s0 + row) * DK_ + quad * 8;
    const bf16x8 a0 = load8b(qbase);
    const bf16x8 a1 = load8b(qbase + 32);
    float il[4];
#pragma unroll
    for (int r = 0; r < 4; ++r)
        il[r] = invl[(size_t)bh * S_ + s0 + quad * 4 + r];

    const __hip_bfloat16* kbase = Kh + (size_t)bh * S_ * DK_;
    float* abase = attn + ((size_t)bh * S_ + s0) * S_;

    for (int t = 0; t < 32; ++t) {
        const int c0 = wave * 512 + t * 16;
        const __hip_bfloat16* kb = kbase + (size_t)(c0 + row) * DK_ + quad * 8;
        f32x4 acc = {0.f, 0.f, 0.f, 0.f};
        acc = mfma16(a0, load8b(kb), acc);
        acc = mfma16(a1, load8b(kb + 32), acc);
        const int col = c0 + row;
#pragma unroll
        for (int r = 0; r < 4; ++r)
            abase[(size_t)(quad * 4 + r) * S_ + col] =
                __expf(acc[r] * 0.125f) * il[r];
    }
}

// ---------------------------------------------------------------------------
// Pass 2 variant: same as attn_kernel, plus bf16 copy of P to workspace
// (same scatter pattern; f2bf matches the rounding pv applied on load).
// ---------------------------------------------------------------------------
__global__ __launch_bounds__(256) void attn_kernel_pb(
    const __hip_bfloat16* __restrict__ Q, const __hip_bfloat16* __restrict__ Kh,
    const float* __restrict__ invl, float* __restrict__ attn,
    short* __restrict__ Pb)
{
    const int wave = threadIdx.x >> 6;
    const int lane = threadIdx.x & 63;
    const int row  = lane & 15;
    const int quad = lane >> 4;
    const int bh = blockIdx.y;
    const int s0 = blockIdx.x * 16;

    const __hip_bfloat16* qbase = Q + ((size_t)bh * S_ + s0 + row) * DK_ + quad * 8;
    const bf16x8 a0 = load8b(qbase);
    const bf16x8 a1 = load8b(qbase + 32);
    float il[4];
#pragma unroll
    for (int r = 0; r < 4; ++r)
        il[r] = invl[(size_t)bh * S_ + s0 + quad * 4 + r];

    const __hip_bfloat16* kbase = Kh + (size_t)bh * S_ * DK_;
    float* abase = attn + ((size_t)bh * S_ + s0) * S_;
    short* pbase = Pb + ((size_t)bh * S_ + s0) * S_;

    for (int t = 0; t < 32; ++t) {
        const int c0 = wave * 512 + t * 16;
        const __hip_bfloat16* kb = kbase + (size_t)(c0 + row) * DK_ + quad * 8;
        f32x4 acc = {0.f, 0.f, 0.f, 0.f};
        acc = mfma16(a0, load8b(kb), acc);
        acc = mfma16(a1, load8b(kb + 32), acc);
        const int col = c0 + row;
#pragma unroll
        for (int r = 0; r < 4; ++r) {
            const float p = __expf(acc[r] * 0.125f) * il[r];
            abase[(size_t)(quad * 4 + r) * S_ + col] = p;
            pbase[(size_t)(quad * 4 + r) * S_ + col] = f2bf(p);
        }
    }
}

// ---------------------------------------------------------------------------
// PV: context = attn @ V. Grid (S/16, B*H); wave = n-tile. (certified fp32 path)
// Vt layout (B,H,DK,S) makes B-fragments contiguous. ctx written (B,S,H,DK).
// ---------------------------------------------------------------------------
__global__ __launch_bounds__(256) void pv_kernel(
    const float* __restrict__ attn, const __hip_bfloat16* __restrict__ Vt,
    __hip_bfloat16* __restrict__ ctx)
{
    const int wave = threadIdx.x >> 6;
    const int lane = threadIdx.x & 63;
    const int row  = lane & 15;
    const int quad = lane >> 4;
    const int bh = blockIdx.y;
    const int b = bh >> 4, h = bh & 15;
    const int m0 = blockIdx.x * 16;
    const int n0 = wave * 16;

    const float* abase = attn + ((size_t)bh * S_ + m0 + row) * S_ + quad * 8;
    const __hip_bfloat16* vbase = Vt + ((size_t)bh * DK_ + n0 + row) * S_ + quad * 8;

    f32x4 acc = {0.f, 0.f, 0.f, 0.f};
    for (int kk = 0; kk < S_; kk += 32)
        acc = mfma16(load8f_bf(abase + kk), load8b(vbase + kk), acc);

    const int d = n0 + row;
#pragma unroll
    for (int r = 0; r < 4; ++r) {
        const int s = m0 + quad * 4 + r;
        ctx[(((size_t)b * S_ + s) * H_ + h) * DK_ + d] = __float2bfloat16(acc[r]);
    }
}

// ---------------------------------------------------------------------------
// PV bf16-P variant: identical indexing, reads Pb (bf16) -> half the fetch,
// no per-element conversion.
// ---------------------------------------------------------------------------
__global__ __launch_bounds__(256) void pv_kernel_pb(
    const short* __restrict__ Pb, const __hip_bfloat16* __restrict__ Vt,
    __hip_bfloat16* __restrict__ ctx)
{
    const int wave = threadIdx.x >> 6;
    const int lane = threadIdx.x & 63;
    const int row  = lane & 15;
    const int quad = lane >> 4;
    const int bh = blockIdx.y;
    const int b = bh >> 4, h = bh & 15;
    const int m0 = blockIdx.x * 16;
    const int n0 = wave * 16;

    const short* abase = Pb + ((size_t)bh * S_ + m0 + row) * S_ + quad * 8;
    const __hip_bfloat16* vbase = Vt + ((size_t)bh * DK_ + n0 + row) * S_ + quad * 8;

    f32x4 acc = {0.f, 0.f, 0.f, 0.f};
    for (int kk = 0; kk < S_; kk += 32)
        acc = mfma16(load8s(abase + kk), load8b(vbase + kk), acc);

    const int d = n0 + row;
#pragma unroll
    for (int r = 0; r < 4; ++r) {
        const int s = m0 + quad * 4 + r;
        ctx[(((size_t)b * S_ + s) * H_ + h) * DK_ + d] = __float2bfloat16(acc[r]);
    }
}

// ---------------------------------------------------------------------------
extern "C" void kernel_launch(void* const* d_in, const int* in_sizes, int n_in,
                              void* d_out, int out_size, void* d_ws, size_t ws_size,
                              hipStream_t stream)
{
    const float* query = (const float*)d_in[0];
    const float* key   = (const float*)d_in[1];
    const float* value = (const float*)d_in[2];
    const float* Wq = (const float*)d_in[3];
    const float* bq = (const float*)d_in[4];
    const float* Wk = (const float*)d_in[5];
    const float* bk = (const float*)d_in[6];
    const float* Wv = (const float*)d_in[7];
    const float* bv = (const float*)d_in[8];
    const float* Wo = (const float*)d_in[9];
    const float* bo = (const float*)d_in[10];

    float* out      = (float*)d_out;
    float* attn_out = out + (size_t)B_ * S_ * D_;

    const size_t NBSD = (size_t)B_ * S_ * D_;     // 4,194,304 elems
    const size_t NDD  = (size_t)D_ * D_;          // 1,048,576 elems
    __hip_bfloat16* q_ws   = (__hip_bfloat16*)d_ws;
    __hip_bfloat16* k_ws   = q_ws + NBSD;
    __hip_bfloat16* vt_ws  = k_ws + NBSD;
    __hip_bfloat16* ctx_ws = vt_ws + NBSD;
    float*          invl   = (float*)(ctx_ws + NBSD);
    short*          pb_ws  = (short*)(invl + (size_t)B_ * H_ * S_);

    // bf16 staging for X/W aliases the head of the Pb region: those buffers
    // are only read by proj_in kernels, all of which complete before
    // attn_kernel_pb writes Pb (stream-ordered). Wo-bf16 is converted into
    // q_ws AFTER attn_kernel_pb (last reader of Q) and used by proj_out.
    short* xq_bf = pb_ws;                 // NBSD
    short* xk_bf = xq_bf + NBSD;          // NBSD
    short* xv_bf = xk_bf + NBSD;          // NBSD
    short* wq_bf = xv_bf + NBSD;          // NDD
    short* wk_bf = wq_bf + NDD;           // NDD
    short* wv_bf = wk_bf + NDD;           // NDD
    short* wo_bf = (short*)q_ws;          // after attn_pb, q_ws is dead

    // bytes needed for the bf16-P fast path (staging fits inside Pb)
    const size_t need_pb = (size_t)NBSD * 2 * 4                 // q,k,vt,ctx
                         + (size_t)B_ * H_ * S_ * 4             // invl
                         + (size_t)B_ * H_ * S_ * S_ * 2;       // Pb
    const bool use_pb = (ws_size >= need_pb);

    dim3 blk(256);
    dim3 gproj(D_ / 16, (B_ * S_) / 64);
    dim3 gatt(S_ / 16, B_ * H_);

    if (use_pb) {
        cvt_bf16_kernel<<<2048, blk, 0, stream>>>(query, xq_bf, (int)NBSD);
        cvt_bf16_kernel<<<2048, blk, 0, stream>>>(key,   xk_bf, (int)NBSD);
        cvt_bf16_kernel<<<2048, blk, 0, stream>>>(value, xv_bf, (int)NBSD);
        cvt_bf16_kernel<<<512,  blk, 0, stream>>>(Wq, wq_bf, (int)NDD);
        cvt_bf16_kernel<<<512,  blk, 0, stream>>>(Wk, wk_bf, (int)NDD);
        cvt_bf16_kernel<<<512,  blk, 0, stream>>>(Wv, wv_bf, (int)NDD);
        proj_in_bf_kernel<<<gproj, blk, 0, stream>>>(xq_bf, wq_bf, bq, q_ws, 0);
        proj_in_bf_kernel<<<gproj, blk, 0, stream>>>(xk_bf, wk_bf, bk, k_ws, 0);
        proj_in_bf_kernel<<<gproj, blk, 0, stream>>>(xv_bf, wv_bf, bv, vt_ws, 1);
        rowsum_kernel<<<gatt, blk, 0, stream>>>(q_ws, k_ws, invl);
        attn_kernel_pb<<<gatt, blk, 0, stream>>>(q_ws, k_ws, invl, attn_out, pb_ws);
        // q_ws dead from here; reuse it for bf16 Wo
        cvt_bf16_kernel<<<512,  blk, 0, stream>>>(Wo, wo_bf, (int)NDD);
        pv_kernel_pb<<<gatt, blk, 0, stream>>>(pb_ws, vt_ws, ctx_ws);
        proj_out_bf_kernel<<<gproj, blk, 0, stream>>>(ctx_ws, wo_bf, bo, out);
    } else {
        proj_in_kernel<<<gproj, blk, 0, stream>>>(query, Wq, bq, q_ws, 0);
        proj_in_kernel<<<gproj, blk, 0, stream>>>(key,   Wk, bk, k_ws, 0);
        proj_in_kernel<<<gproj, blk, 0, stream>>>(value, Wv, bv, vt_ws, 1);
        rowsum_kernel<<<gatt, blk, 0, stream>>>(q_ws, k_ws, invl);
        attn_kernel<<<gatt, blk, 0, stream>>>(q_ws, k_ws, invl, attn_out);
        pv_kernel<<<gatt, blk, 0, stream>>>(attn_out, vt_ws, ctx_ws);
        proj_out_kernel<<<gproj, blk, 0, stream>>>(ctx_ws, Wo, bo, out);
    }
}